// Round 2
// baseline (996.987 us; speedup 1.0000x reference)
//
#include <hip/hip_runtime.h>
#include <hip/hip_bf16.h>
#include <cstdint>

#define NROWS 8192
#define DDIM  1024
#define QBLK  32
#define KVT   128
#define DC    64
#define NW    8
#define NITER (NROWS / KVT)
#define NDC   (DDIM / DC)
#define LOG2E 1.44269504088896340736f

typedef __attribute__((ext_vector_type(4))) float f32x4;
typedef __attribute__((ext_vector_type(8))) short bf16x8;
typedef unsigned short u16;

__device__ __forceinline__ u16 f2bf(float f) {
  uint32_t u = __builtin_bit_cast(uint32_t, f);
  uint32_t r = u + 0x7FFFu + ((u >> 16) & 1u);  // round-to-nearest-even
  return (u16)(r >> 16);
}

// Prep: xbf = bf16(x) row-major [N][D]; xbfT = bf16(x)^T [D][N]
__global__ __launch_bounds__(256) void prep_kernel(const float* __restrict__ x,
                                                   u16* __restrict__ xbf,
                                                   u16* __restrict__ xbfT) {
  __shared__ __align__(16) u16 T[64][72];
  const int t = threadIdx.x;
  const int n0 = blockIdx.x * 64;  // 128 tiles along N
  const int d0 = blockIdx.y * 64;  // 16 tiles along D
#pragma unroll
  for (int rr = 0; rr < 4; ++rr) {
    const int row = (t >> 4) + rr * 16;
    const int c4 = (t & 15) * 4;
    const float4 v = *reinterpret_cast<const float4*>(&x[(size_t)(n0 + row) * DDIM + d0 + c4]);
    ushort4 b;
    b.x = f2bf(v.x); b.y = f2bf(v.y); b.z = f2bf(v.z); b.w = f2bf(v.w);
    *reinterpret_cast<ushort4*>(&xbf[(size_t)(n0 + row) * DDIM + d0 + c4]) = b;
    *reinterpret_cast<ushort4*>(&T[row][c4]) = b;
  }
  __syncthreads();
#pragma unroll
  for (int rr = 0; rr < 4; ++rr) {
    const int drow = (t >> 4) + rr * 16;
    const int nc = (t & 15) * 4;
    ushort4 o;
    o.x = T[nc + 0][drow]; o.y = T[nc + 1][drow];
    o.z = T[nc + 2][drow]; o.w = T[nc + 3][drow];
    *reinterpret_cast<ushort4*>(&xbfT[(size_t)(d0 + drow) * NROWS + n0 + nc]) = o;
  }
}

// Flash attention: one block per 32 q-rows, 8 waves.
// Wave w: S-phase kv slice [w*16, w*16+16); PV-phase O columns [w*128, w*128+128).
__global__ __launch_bounds__(512, 2) void attn_kernel(const u16* __restrict__ xbf,
                                                      const u16* __restrict__ xbfT,
                                                      float* __restrict__ out) {
  // +8 u16 pad per row => row stride 144B (4-bank offset) kills 16-way conflicts
  __shared__ __align__(16) u16 Qs[2][QBLK][DC + 8];
  __shared__ __align__(16) u16 Ks[2][KVT][DC + 8];
  __shared__ __align__(16) u16 Ps[QBLK][KVT + 8];
  __shared__ float smax[NW][QBLK];
  __shared__ float ssum[NW][QBLK];

  const int tid = threadIdx.x;
  const int w = tid >> 6;
  const int lane = tid & 63;
  const int g = lane >> 4;
  const int ln16 = lane & 15;
  const int j = lane & 31;           // stat row owned by this lane
  const int q0 = blockIdx.x * QBLK;

  // staging maps
  const int kr = tid >> 2, kc = (tid & 3) * 16;   // K chunk: 128 rows x 64 cols
  const int qr = tid >> 4, qc = (tid & 15) * 4;   // Q chunk: 32 rows x 64 cols

  int4 rk0, rk1; ushort4 rq;  // in-flight staging registers (T14 split)

  auto load_chunk = [&](int t_, int dc_) {
    const size_t ko = (size_t)(t_ * KVT + kr) * DDIM + dc_ * DC + kc;
    rk0 = *reinterpret_cast<const int4*>(&xbf[ko]);
    rk1 = *reinterpret_cast<const int4*>(&xbf[ko + 8]);
    const size_t qo = (size_t)(q0 + qr) * DDIM + dc_ * DC + qc;
    rq = *reinterpret_cast<const ushort4*>(&xbf[qo]);
  };
  auto write_chunk = [&](int buf) {
    *reinterpret_cast<int4*>(&Ks[buf][kr][kc]) = rk0;
    *reinterpret_cast<int4*>(&Ks[buf][kr][kc + 8]) = rk1;
    *reinterpret_cast<ushort4*>(&Qs[buf][qr][qc]) = rq;
  };

  f32x4 oacc[2][8];
#pragma unroll
  for (int f = 0; f < 2; ++f)
#pragma unroll
    for (int c = 0; c < 8; ++c) oacc[f][c] = (f32x4){0.f, 0.f, 0.f, 0.f};
  float m_run = -INFINITY, l_run = 0.0f;

  load_chunk(0, 0);

  for (int t = 0; t < NITER; ++t) {
    // ---------------- S = Q K^T over D (chunked, double-buffered) ----------
    f32x4 sacc[2] = {{0.f,0.f,0.f,0.f},{0.f,0.f,0.f,0.f}};
    for (int dc = 0; dc < NDC; ++dc) {
      const int buf = dc & 1;
      write_chunk(buf);                       // regs -> LDS (waits vmcnt)
      if (dc + 1 < NDC) load_chunk(t, dc + 1);           // issue next loads
      else if (t + 1 < NITER) load_chunk(t + 1, 0);      // cross-iter prefetch
      __syncthreads();                        // chunk dc visible to all
#pragma unroll
      for (int kk = 0; kk < 2; ++kk) {
        const int kq = kk * 32 + g * 8;
        bf16x8 a0 = *reinterpret_cast<const bf16x8*>(&Qs[buf][ln16][kq]);
        bf16x8 a1 = *reinterpret_cast<const bf16x8*>(&Qs[buf][16 + ln16][kq]);
        bf16x8 b  = *reinterpret_cast<const bf16x8*>(&Ks[buf][w * 16 + ln16][kq]);
        sacc[0] = __builtin_amdgcn_mfma_f32_16x16x32_bf16(a0, b, sacc[0], 0, 0, 0);
        sacc[1] = __builtin_amdgcn_mfma_f32_16x16x32_bf16(a1, b, sacc[1], 0, 0, 0);
      }
    }
    // S frag: row q = g*4+r (+16*f), col kv = w*16 + ln16

    // ---------------- online softmax (cross-wave via LDS stats) ------------
    float rmx[2][4];
#pragma unroll
    for (int f = 0; f < 2; ++f)
#pragma unroll
      for (int r = 0; r < 4; ++r) {
        float v = sacc[f][r];
        v = fmaxf(v, __shfl_xor(v, 1, 16));
        v = fmaxf(v, __shfl_xor(v, 2, 16));
        v = fmaxf(v, __shfl_xor(v, 4, 16));
        v = fmaxf(v, __shfl_xor(v, 8, 16));
        rmx[f][r] = v;
      }
    if (ln16 == 0) {
#pragma unroll
      for (int f = 0; f < 2; ++f)
#pragma unroll
        for (int r = 0; r < 4; ++r) smax[w][f * 16 + g * 4 + r] = rmx[f][r];
    }
    __syncthreads();
    float tm = smax[0][j];
#pragma unroll
    for (int wv = 1; wv < NW; ++wv) tm = fmaxf(tm, smax[wv][j]);
    const float mnew = fmaxf(m_run, tm);
    const float alpha = exp2f((m_run - mnew) * LOG2E);
    m_run = mnew;

    float mrow[2][4], arow[2][4];
#pragma unroll
    for (int f = 0; f < 2; ++f)
#pragma unroll
      for (int r = 0; r < 4; ++r) {
        const int row = f * 16 + g * 4 + r;
        mrow[f][r] = __shfl(mnew, row);
        arow[f][r] = __shfl(alpha, row);
      }

    float prb[2][4], rs[2][4];
#pragma unroll
    for (int f = 0; f < 2; ++f)
#pragma unroll
      for (int r = 0; r < 4; ++r) {
        const float p = exp2f((sacc[f][r] - mrow[f][r]) * LOG2E);
        prb[f][r] = p;
        float s = p;
        s += __shfl_xor(s, 1, 16);
        s += __shfl_xor(s, 2, 16);
        s += __shfl_xor(s, 4, 16);
        s += __shfl_xor(s, 8, 16);
        rs[f][r] = s;
      }
    if (ln16 == 0) {
#pragma unroll
      for (int f = 0; f < 2; ++f)
#pragma unroll
        for (int r = 0; r < 4; ++r) ssum[w][f * 16 + g * 4 + r] = rs[f][r];
    }
#pragma unroll
    for (int f = 0; f < 2; ++f)
#pragma unroll
      for (int r = 0; r < 4; ++r)
        Ps[f * 16 + g * 4 + r][w * 16 + ln16] = f2bf(prb[f][r]);
    __syncthreads();

    float ts = ssum[0][j];
#pragma unroll
    for (int wv = 1; wv < NW; ++wv) ts += ssum[wv][j];
    l_run = l_run * alpha + ts;

    // rescale O by alpha (per q-row)
#pragma unroll
    for (int f = 0; f < 2; ++f)
#pragma unroll
      for (int cf = 0; cf < 8; ++cf)
#pragma unroll
        for (int r = 0; r < 4; ++r) oacc[f][cf][r] *= arow[f][r];

    // ---------------- O += P V  (V fragments from transposed bf16 copy) ----
    const int kvb = t * KVT;
#pragma unroll
    for (int kk = 0; kk < 4; ++kk) {
      bf16x8 pa0 = *reinterpret_cast<const bf16x8*>(&Ps[ln16][kk * 32 + g * 8]);
      bf16x8 pa1 = *reinterpret_cast<const bf16x8*>(&Ps[16 + ln16][kk * 32 + g * 8]);
#pragma unroll
      for (int cf = 0; cf < 8; ++cf) {
        const int c = w * 128 + cf * 16 + ln16;
        const int4 vv = *reinterpret_cast<const int4*>(
            &xbfT[(size_t)c * NROWS + kvb + kk * 32 + g * 8]);
        const bf16x8 vb = __builtin_bit_cast(bf16x8, vv);
        oacc[0][cf] = __builtin_amdgcn_mfma_f32_16x16x32_bf16(pa0, vb, oacc[0][cf], 0, 0, 0);
        oacc[1][cf] = __builtin_amdgcn_mfma_f32_16x16x32_bf16(pa1, vb, oacc[1][cf], 0, 0, 0);
      }
    }
  }

  // ---------------- epilogue: out = O / l ---------------------------------
  const float rinv = 1.0f / l_run;
  float rrow[2][4];
#pragma unroll
  for (int f = 0; f < 2; ++f)
#pragma unroll
    for (int r = 0; r < 4; ++r) rrow[f][r] = __shfl(rinv, f * 16 + g * 4 + r);
#pragma unroll
  for (int f = 0; f < 2; ++f)
#pragma unroll
    for (int cf = 0; cf < 8; ++cf)
#pragma unroll
      for (int r = 0; r < 4; ++r) {
        const int row = q0 + f * 16 + g * 4 + r;
        const int c = w * 128 + cf * 16 + ln16;
        out[(size_t)row * DDIM + c] = oacc[f][cf][r] * rrow[f][r];
      }
}

extern "C" void kernel_launch(void* const* d_in, const int* in_sizes, int n_in,
                              void* d_out, int out_size, void* d_ws, size_t ws_size,
                              hipStream_t stream) {
  const float* x = (const float*)d_in[0];
  u16* xbf  = (u16*)d_ws;                        // 16 MB
  u16* xbfT = xbf + (size_t)NROWS * DDIM;        // 16 MB
  float* out = (float*)d_out;

  hipLaunchKernelGGL(prep_kernel, dim3(NROWS / 64, DDIM / 64), dim3(256), 0, stream,
                     x, xbf, xbfT);
  hipLaunchKernelGGL(attn_kernel, dim3(NROWS / QBLK), dim3(512), 0, stream,
                     xbf, xbfT, out);
}